// Round 8
// baseline (211.061 us; speedup 1.0000x reference)
//
#include <hip/hip_runtime.h>
#include <math.h>

#define T_TOK 8192
#define D_DIM 512
#define H_DIM 1024
#define NE    8
#define NGB   2048  // gating blocks (4 tokens each) = hist granularity
#define NSB   64    // scatter blocks (256 entries each)

typedef __attribute__((ext_vector_type(8))) short bf16x8;
typedef __attribute__((ext_vector_type(4))) float f32x4;
typedef __attribute__((ext_vector_type(4))) unsigned short us4;
typedef __attribute__((ext_vector_type(8))) unsigned short us8;

// ---------------- workspace layout (bytes) ----------------
// 0       counts[8] | 32 importance[8] | 64 offsets[8]
// 128     top_e[16384] int      (64 KB)
// 65664   top_p[16384] float    (64 KB)
// 131200  tok_list[16384] int
// 262400  hist[2048][8] int (64 KB) | 328064 impp[2048][8] float (64 KB)
// 393728  bb[64][8] int
// 395776  inv_slot[16384] int  (64 KB)
// 1 MB    XB   bf16 [8192][512]      8 MB   (dead after stage1)
// 9 MB    W1T  bf16 [8][1024][512]   8 MB   (dead after stage1)
// 1 MB    EO   bf16 [16384][512]    16 MB   (aliases XB+W1T, written by stage2)
// 17 MB   W2T  bf16 [8][512][1024]   8 MB
// 25 MB   HBUF bf16 [16384][1024]   32 MB

__device__ __forceinline__ unsigned short f2bf(float f) {
  union { float f; unsigned int u; } v; v.f = f;
  const unsigned int u = v.u;
  return (unsigned short)((u + 0x7fffu + ((u >> 16) & 1u)) >> 16);  // RNE
}

__device__ __forceinline__ float bf2f(unsigned short b) {
  union { unsigned int u; float f; } v; v.u = ((unsigned int)b) << 16;
  return v.f;
}

__device__ __forceinline__ void gload16(const void* g, void* l) {
  __builtin_amdgcn_global_load_lds(
      (const __attribute__((address_space(1))) void*)g,
      (__attribute__((address_space(3))) void*)l, 16, 0, 0);
}

// ---------------- gating: logits, top-2, softmax + x->bf16 + LDS histogram ----------------
__global__ __launch_bounds__(256) void gating_kernel(
    const float* __restrict__ x, const float* __restrict__ Wg,
    unsigned short* __restrict__ XB,
    int* __restrict__ top_e, float* __restrict__ top_p,
    int* __restrict__ hist, float* __restrict__ impp)
{
  __shared__ float wgs[NE][D_DIM];
  __shared__ int   h[NE];
  __shared__ float im[NE];
  const int tid = threadIdx.x;
  for (int i = tid; i < D_DIM * NE; i += 256)
    wgs[i & 7][i >> 3] = Wg[i];
  if (tid < NE) { h[tid] = 0; im[tid] = 0.f; }
  __syncthreads();

  const int lane = tid & 63;
  const int wave = tid >> 6;
  const int t = blockIdx.x * 4 + wave;

  float acc[NE];
#pragma unroll
  for (int e = 0; e < NE; e++) acc[e] = 0.f;
#pragma unroll
  for (int j = 0; j < 8; j++) {
    const int d = lane + j * 64;
    const float xv = x[(size_t)t * D_DIM + d];
    XB[(size_t)t * D_DIM + d] = f2bf(xv);       // fused x->bf16 (coalesced 2B/lane)
#pragma unroll
    for (int e = 0; e < NE; e++) acc[e] += xv * wgs[e][d];
  }
#pragma unroll
  for (int e = 0; e < NE; e++) {
#pragma unroll
    for (int m = 32; m > 0; m >>= 1) acc[e] += __shfl_xor(acc[e], m);
  }

  if (lane == 0) {
    int i0 = 0; float v0 = acc[0];
#pragma unroll
    for (int e = 1; e < NE; e++) if (acc[e] > v0) { v0 = acc[e]; i0 = e; }
    int i1 = -1; float v1 = -3.4e38f;
#pragma unroll
    for (int e = 0; e < NE; e++) if (e != i0 && acc[e] > v1) { v1 = acc[e]; i1 = e; }

    const float ex = __expf(v1 - v0);
    const float inv = 1.f / (1.f + ex);
    const float p0 = inv, p1 = ex * inv;
    top_e[t * 2 + 0] = i0; top_e[t * 2 + 1] = i1;
    top_p[t * 2 + 0] = p0; top_p[t * 2 + 1] = p1;
    atomicAdd(&h[i0], 1);  atomicAdd(&h[i1], 1);     // LDS atomics only
    atomicAdd(&im[i0], p0); atomicAdd(&im[i1], p1);
  }
  __syncthreads();
  if (tid < NE) {
    hist[blockIdx.x * NE + tid] = h[tid];
    impp[blockIdx.x * NE + tid] = im[tid];
  }
}

// ---------------- W1/W2 -> bf16, transposed per expert (64x64 tiles) ----------------
__global__ __launch_bounds__(256) void wtrans_kernel(
    const float* __restrict__ W1, const float* __restrict__ W2,
    unsigned short* __restrict__ W1T, unsigned short* __restrict__ W2T) {
  __shared__ unsigned short lds[64][76];   // stride 152B: 8B-aligned, banks staggered
  int bid = blockIdx.x;
  const float* src; unsigned short* dst; int R, C, lc;
  if (bid < 1024) { src = W1; dst = W1T; R = D_DIM; C = H_DIM; lc = 4; }
  else { bid -= 1024; src = W2; dst = W2T; R = H_DIM; C = D_DIM; lc = 3; }
  const int e = bid >> 7;                 // 128 tiles per expert
  const int rem = bid & 127;
  const int rt = rem >> lc;
  const int ct = rem & ((C >> 6) - 1);
  const size_t ebase = (size_t)e * R * C;
  const int tid = threadIdx.x;
#pragma unroll
  for (int it = 0; it < 4; it++) {        // read 64x64 f32, cvt to bf16 in LDS
    const int idx = it * 256 + tid;
    const int r = idx >> 4, c0 = (idx & 15) * 4;
    const float4 v = *reinterpret_cast<const float4*>(
        &src[ebase + (size_t)(rt * 64 + r) * C + ct * 64 + c0]);
    us4 o; o[0] = f2bf(v.x); o[1] = f2bf(v.y); o[2] = f2bf(v.z); o[3] = f2bf(v.w);
    *reinterpret_cast<us4*>(&lds[r][c0]) = o;
  }
  __syncthreads();
#pragma unroll
  for (int it = 0; it < 2; it++) {        // write transposed, 16B/lane full lines
    const int idx = it * 256 + tid;
    const int dc = idx >> 3;              // dst row (source col), 0..63
    const int c8 = idx & 7;               // 8 us8 chunks per dst row
    us8 o;
#pragma unroll
    for (int m = 0; m < 8; m++) o[m] = lds[c8 * 8 + m][dc];
    *reinterpret_cast<us8*>(&dst[ebase + (size_t)(ct * 64 + dc) * R + rt * 64 + c8 * 8]) = o;
  }
}

// ---------------- finalize: parallel reduce + offsets + losses + scatter bases ----------------
__global__ __launch_bounds__(512) void finalize_kernel(
    const int* __restrict__ hist, const float* __restrict__ impp,
    int* __restrict__ counts, float* __restrict__ importance,
    int* __restrict__ offsets, int* __restrict__ bb,
    float* __restrict__ out_tail)
{
  __shared__ int   ccnt[NSB][NE];   // per-scatter-block chunk sums
  __shared__ float cimp[NSB][NE];
  __shared__ int   cnt_s[NE];
  __shared__ float imp_s[NE];
  __shared__ int   off_s[NE];
  const int tid = threadIdx.x;
  // phase A: 512 threads, each sums 32 gating blocks for one (scatter-blk, expert)
  {
    const int s = tid >> 3, e = tid & 7;
    int c = 0; float im = 0.f;
#pragma unroll 8
    for (int j = 0; j < 32; j++) {
      c  += hist[(s * 32 + j) * NE + e];
      im += impp[(s * 32 + j) * NE + e];
    }
    ccnt[s][e] = c; cimp[s][e] = im;
  }
  __syncthreads();
  // phase B: per-expert totals
  if (tid < NE) {
    int cc = 0; float ss = 0.f;
#pragma unroll 8
    for (int q = 0; q < NSB; q++) { cc += ccnt[q][tid]; ss += cimp[q][tid]; }
    cnt_s[tid] = cc; imp_s[tid] = ss;
    counts[tid] = cc; importance[tid] = ss;
  }
  __syncthreads();
  // phase C: offsets + losses (scalar, trivial)
  if (tid == 0) {
    int off = 0;
    for (int e = 0; e < NE; e++) { off_s[e] = off; offsets[e] = off; off += cnt_s[e]; }
    float mi = 0.f, ml = 0.f;
    for (int e = 0; e < NE; e++) { mi += imp_s[e]; ml += (float)cnt_s[e]; }
    mi *= (1.f / NE); ml *= (1.f / NE);
    float vi = 0.f, vl = 0.f;
    for (int e = 0; e < NE; e++) {
      const float di = imp_s[e] - mi; vi += di * di;
      const float dl = (float)cnt_s[e] - ml; vl += dl * dl;
    }
    vi *= (1.f / (NE - 1)); vl *= (1.f / (NE - 1));   // ddof=1
    out_tail[0] = vi / (mi * mi + 1e-10f);
    out_tail[1] = vl / (ml * ml + 1e-10f);
  }
  __syncthreads();
  // phase D: scatter-block bases (64-step LDS walk per expert)
  if (tid < NE) {
    int run = off_s[tid];
    for (int q = 0; q < NSB; q++) { bb[q * NE + tid] = run; run += ccnt[q][tid]; }
  }
}

// ---------------- scatter: slot assignment via LDS cursors + inverse map ----------------
__global__ __launch_bounds__(256) void scatter_kernel(
    const int* __restrict__ top_e, const int* __restrict__ bb,
    int* __restrict__ tok_list, int* __restrict__ inv_slot)
{
  __shared__ int cur[NE];
  const int tid = threadIdx.x;
  if (tid < NE) cur[tid] = bb[blockIdx.x * NE + tid];
  __syncthreads();
  const int i = blockIdx.x * 256 + tid;
  const int e = top_e[i];
  const int pos = atomicAdd(&cur[e], 1);   // LDS atomic: intra-block only
  tok_list[pos] = i >> 1;
  inv_slot[i] = pos;
}

// ---------------- MFMA expert GEMM: 256x256 tile, 8 waves (2Mx4N), 128x64/wave,
//                  counted-vmcnt 2-tile-lookahead pipeline (no vmcnt(0) drain in loop)
// STAGE2=false: Hout[slot][h] = relu(C + b1)  (OD=H_DIM)
// STAGE2=true : Hout[slot][d] =      C + b2   (OD=D_DIM, un-gated expert output)
template<int KD, int MT, bool STAGE2>
__global__ __launch_bounds__(512, 1) void expert_gemm_kernel(
    const unsigned short* __restrict__ Wt,
    const unsigned short* __restrict__ Bsrc,
    const float* __restrict__ bias,
    const int* __restrict__ counts, const int* __restrict__ offsets,
    const int* __restrict__ tok_list,
    unsigned short* __restrict__ Hout)
{
  constexpr int M = MT * 256;
  constexpr int LMT = (MT == 4) ? 2 : 1;
  constexpr int OD = STAGE2 ? D_DIM : H_DIM;
  constexpr int NK = KD / 64;
  const int e = blockIdx.x & 7;          // expert -> fixed XCD for weight L2 residency
  const int tmp = blockIdx.x >> 3;
  const int mtile = tmp & (MT - 1);
  const int ttile = tmp >> LMT;          // 0..63 covers any routing imbalance
  const int cnt = counts[e];
  if (ttile * 256 >= cnt) return;
  const int base = offsets[e] + ttile * 256;
  const int rem = cnt - ttile * 256;
  const int nvalid = rem < 256 ? rem : 256;

  // [buf][mat(0=A weights,1=B tokens)][row][col]: 2*2*256*64*2B = 128 KB
  __shared__ unsigned short lds[2][2][256][64];

  const int tid = threadIdx.x;
  const int lane = tid & 63;
  const int wave = tid >> 6;      // 0..7
  const int wm = wave >> 2;       // m-half (128 rows)
  const int wn = wave & 3;        // n-quarter (64 cols)

  // staging: 4 x 16B segs per thread per matrix per K-tile; LDS dest linear,
  // swizzle applied on the GLOBAL column (both-sides involution)
  const unsigned short* wsrc[4];
  const unsigned short* bsrc[4];
#pragma unroll
  for (int i = 0; i < 4; i++) {
    const int seg = tid + i * 512;
    const int row = seg >> 3;            // 0..255
    const int s = seg & 7;
    const int scol = (s ^ (row & 7)) << 3;
    wsrc[i] = Wt + ((size_t)e * M + (size_t)(mtile * 256 + row)) * KD + scol;
    const int cr = (row < nvalid) ? row : (nvalid - 1);
    const int brow = STAGE2 ? (base + cr) : tok_list[base + cr];
    bsrc[i] = Bsrc + (size_t)brow * KD + scol;
  }
  const int ldso = wave * 512;   // elems; HW adds lane*16B; i-step adds 4096 elems

  f32x4 acc[8][4];
#pragma unroll
  for (int a = 0; a < 8; a++)
#pragma unroll
    for (int nj = 0; nj < 4; nj++)
#pragma unroll
      for (int q = 0; q < 4; q++) acc[a][nj][q] = 0.f;

#define STAGE_TILE(t_)                                                        \
  {                                                                           \
    const int buf_ = (t_) & 1;                                                \
    const int k0_ = (t_) * 64;                                                \
    _Pragma("unroll")                                                         \
    for (int i = 0; i < 4; i++) {                                             \
      gload16(wsrc[i] + k0_, &lds[buf_][0][0][0] + ldso + i * 4096);          \
      gload16(bsrc[i] + k0_, &lds[buf_][1][0][0] + ldso + i * 4096);          \
    }                                                                         \
  }

  // prologue: stage K-tiles 0 and 1; wait tile 0 only (8 of 16 loads)
  STAGE_TILE(0)
  STAGE_TILE(1)
  asm volatile("s_waitcnt vmcnt(8)" ::: "memory");
  __builtin_amdgcn_s_barrier();

  for (int t = 0; t < NK; ++t) {
    const int buf = t & 1;
    bf16x8 breg[4][2], areg[4][2];
    // ds_read: all B frags + A half-0 frags of this wave
#pragma unroll
    for (int nj = 0; nj < 4; nj++) {
      const int r = wn * 64 + nj * 16 + (lane & 15);
#pragma unroll
      for (int ks = 0; ks < 2; ks++) {
        const int sl = ((ks * 4 + (lane >> 4)) ^ (r & 7)) << 3;
        breg[nj][ks] = *reinterpret_cast<const bf16x8*>(&lds[buf][1][r][sl]);
      }
    }
#pragma unroll
    for (int mi = 0; mi < 4; mi++) {
      const int m = wm * 128 + mi * 16 + (lane & 15);
#pragma unroll
      for (int ks = 0; ks < 2; ks++) {
        const int sl = ((ks * 4 + (lane >> 4)) ^ (m & 7)) << 3;
        areg[mi][ks] = *reinterpret_cast<const bf16x8*>(&lds[buf][0][m][sl]);
      }
    }
    // MFMA half 0 (t+1 loads still in flight underneath)
    __builtin_amdgcn_s_setprio(1);
#pragma unroll
    for (int ks = 0; ks < 2; ks++)
#pragma unroll
      for (int mi = 0; mi < 4; mi++)
#pragma unroll
        for (int nj = 0; nj < 4; nj++)
          acc[mi][nj] = __builtin_amdgcn_mfma_f32_16x16x32_bf16(areg[mi][ks], breg[nj][ks], acc[mi][nj], 0, 0, 0);
    __builtin_amdgcn_s_setprio(0);
    // ds_read: A half-1 (still current buf — must finish before restaging it)
#pragma unroll
    for (int mi = 0; mi < 4; mi++) {
      const int m = wm * 128 + 64 + mi * 16 + (lane & 15);
#pragma unroll
      for (int ks = 0; ks < 2; ks++) {
        const int sl = ((ks * 4 + (lane >> 4)) ^ (m & 7)) << 3;
        areg[mi][ks] = *reinterpret_cast<const bf16x8*>(&lds[buf][0][m][sl]);
      }
    }
    asm volatile("s_waitcnt lgkmcnt(0)" ::: "memory");   // this wave done reading buf
    __builtin_amdgcn_s_barrier();                        // all waves done reading buf
    if (t + 2 < NK) {
      STAGE_TILE(t + 2)                                  // overwrite buf (now free)
      asm volatile("s_waitcnt vmcnt(8)" ::: "memory");   // t+1 landed; t+2 stays in flight
    } else {
      asm volatile("s_waitcnt vmcnt(0)" ::: "memory");   // tail only
    }
    __builtin_amdgcn_s_barrier();                        // t+1 visible to all waves
    // MFMA half 1
    __builtin_amdgcn_s_setprio(1);
#pragma unroll
    for (int ks = 0; ks < 2; ks++)
#pragma unroll
      for (int mi = 0; mi < 4; mi++)
#pragma unroll
        for (int nj = 0; nj < 4; nj++)
          acc[4 + mi][nj] = __builtin_amdgcn_mfma_f32_16x16x32_bf16(areg[mi][ks], breg[nj][ks], acc[4 + mi][nj], 0, 0, 0);
    __builtin_amdgcn_s_setprio(0);
  }
#undef STAGE_TILE

  // epilogue: acc[a][nj] -> m = wm*128 + (a>>2)*64 + (a&3)*16 + (lane>>4)*4 + j
  //                         n = wn*64 + nj*16 + (lane&15)   (slot within tile)
#pragma unroll
  for (int a = 0; a < 8; a++) {
    const int mb = mtile * 256 + wm * 128 + (a >> 2) * 64 + (a & 3) * 16 + ((lane >> 4) << 2);
    float bv[4];
#pragma unroll
    for (int j = 0; j < 4; j++) bv[j] = bias[e * M + mb + j];
#pragma unroll
    for (int nj = 0; nj < 4; nj++) {
      const int r = wn * 64 + nj * 16 + (lane & 15);
      if (r < nvalid) {
        us4 o;
#pragma unroll
        for (int j = 0; j < 4; j++) {
          const float v = acc[a][nj][j] + bv[j];
          o[j] = f2bf(STAGE2 ? v : fmaxf(v, 0.f));
        }
        *reinterpret_cast<us4*>(&Hout[(size_t)(base + r) * OD + mb]) = o;
      }
    }
  }
}

// ---------------- combine: out[t] = p0*EO[s0] + p1*EO[s1] ----------------
__global__ __launch_bounds__(256) void combine_kernel(
    const unsigned short* __restrict__ EO,
    const int* __restrict__ inv_slot, const float* __restrict__ top_p,
    float* __restrict__ out)
{
  const int idx = blockIdx.x * 256 + threadIdx.x;
  const int t  = idx >> 6;            // 64 threads per token (512/8)
  const int d0 = (idx & 63) * 8;
  const int s0 = inv_slot[t * 2 + 0];
  const int s1 = inv_slot[t * 2 + 1];
  const float p0 = top_p[t * 2 + 0];
  const float p1 = top_p[t * 2 + 1];
  const us8 a = *reinterpret_cast<const us8*>(&EO[(size_t)s0 * D_DIM + d0]);
  const us8 b = *reinterpret_cast<const us8*>(&EO[(size_t)s1 * D_DIM + d0]);
  float4 o0, o1;
  o0.x = p0 * bf2f(a[0]) + p1 * bf2f(b[0]);
  o0.y = p0 * bf2f(a[1]) + p1 * bf2f(b[1]);
  o0.z = p0 * bf2f(a[2]) + p1 * bf2f(b[2]);
  o0.w = p0 * bf2f(a[3]) + p1 * bf2f(b[3]);
  o1.x = p0 * bf2f(a[4]) + p1 * bf2f(b[4]);
  o1.y = p0 * bf2f(a[5]) + p1 * bf2f(b[5]);
  o1.z = p0 * bf2f(a[6]) + p1 * bf2f(b[6]);
  o1.w = p0 * bf2f(a[7]) + p1 * bf2f(b[7]);
  float* op = &out[(size_t)t * D_DIM + d0];
  *reinterpret_cast<float4*>(op)     = o0;
  *reinterpret_cast<float4*>(op + 4) = o1;
}

// ---------------- launcher ----------------
extern "C" void kernel_launch(void* const* d_in, const int* in_sizes, int n_in,
                              void* d_out, int out_size, void* d_ws, size_t ws_size,
                              hipStream_t stream)
{
  const float* x  = (const float*)d_in[0];
  const float* Wg = (const float*)d_in[1];
  const float* W1 = (const float*)d_in[2];
  const float* b1 = (const float*)d_in[3];
  const float* W2 = (const float*)d_in[4];
  const float* b2 = (const float*)d_in[5];
  float* out = (float*)d_out;

  char* ws = (char*)d_ws;
  int*   counts     = (int*)(ws + 0);
  float* importance = (float*)(ws + 32);
  int*   offsets    = (int*)(ws + 64);
  int*   top_e      = (int*)(ws + 128);
  float* top_p      = (float*)(ws + 128 + 65536);
  int*   tok_list   = (int*)(ws + 128 + 131072);
  int*   hist       = (int*)(ws + 262400);
  float* impp       = (float*)(ws + 328064);
  int*   bb         = (int*)(ws + 393728);
  int*   inv_slot   = (int*)(ws + 395776);
  unsigned short* XB   = (unsigned short*)(ws + (1ull << 20));
  unsigned short* W1T  = (unsigned short*)(ws + (9ull << 20));
  unsigned short* W2T  = (unsigned short*)(ws + (17ull << 20));
  unsigned short* HBUF = (unsigned short*)(ws + (25ull << 20));
  unsigned short* EO   = (unsigned short*)(ws + (1ull << 20));  // aliases XB+W1T (dead after stage1)

  gating_kernel<<<NGB, 256, 0, stream>>>(x, Wg, XB, top_e, top_p, hist, impp);
  wtrans_kernel<<<2048, 256, 0, stream>>>(W1, W2, W1T, W2T);
  finalize_kernel<<<1, 512, 0, stream>>>(hist, impp, counts, importance, offsets, bb,
                                         out + (size_t)T_TOK * D_DIM);
  scatter_kernel<<<NSB, 256, 0, stream>>>(top_e, bb, tok_list, inv_slot);
  // stage 1: HBUF = relu(x @ W1 + b1)   (M=1024 -> MT=4, K=512)
  expert_gemm_kernel<512, 4, false><<<8 * 4 * 64, 512, 0, stream>>>(
      W1T, XB, b1, counts, offsets, tok_list, HBUF);
  // stage 2: EO = HBUF @ W2 + b2        (M=512 -> MT=2, K=1024)
  expert_gemm_kernel<1024, 2, true><<<8 * 2 * 64, 512, 0, stream>>>(
      W2T, HBUF, b2, counts, offsets, tok_list, EO);
  // combine: out[t] = p0*EO[s0] + p1*EO[s1]
  combine_kernel<<<T_TOK * D_DIM / (256 * 8), 256, 0, stream>>>(EO, inv_slot, top_p, out);
}

// Round 9
// 194.672 us; speedup vs baseline: 1.0842x; 1.0842x over previous
//
#include <hip/hip_runtime.h>
#include <math.h>

#define T_TOK 8192
#define D_DIM 512
#define H_DIM 1024
#define NE    8
#define NGB   2048  // gating blocks (4 tokens each) = hist granularity
#define NSB   64    // scatter blocks (256 entries each)

typedef __attribute__((ext_vector_type(8))) short bf16x8;
typedef __attribute__((ext_vector_type(4))) float f32x4;
typedef __attribute__((ext_vector_type(4))) unsigned short us4;
typedef __attribute__((ext_vector_type(8))) unsigned short us8;

// ---------------- workspace layout (bytes) ----------------
// 0       counts[8] | 32 importance[8] | 64 offsets[8]
// 128     top_e[16384] int      (64 KB)
// 65664   top_p[16384] float    (64 KB)
// 131200  tok_list[16384] int
// 262400  hist[2048][8] int (64 KB) | 328064 impp[2048][8] float (64 KB)
// 393728  bb[64][8] int
// 395776  inv_slot[16384] int  (64 KB)
// 1 MB    XB   bf16 [8192][512]      8 MB   (dead after stage1)
// 9 MB    W1T  bf16 [8][1024][512]   8 MB   (dead after stage1)
// 1 MB    EO   bf16 [16384][512]    16 MB   (aliases XB+W1T, written by stage2)
// 17 MB   W2T  bf16 [8][512][1024]   8 MB
// 25 MB   HBUF bf16 [16384][1024]   32 MB

__device__ __forceinline__ unsigned short f2bf(float f) {
  union { float f; unsigned int u; } v; v.f = f;
  const unsigned int u = v.u;
  return (unsigned short)((u + 0x7fffu + ((u >> 16) & 1u)) >> 16);  // RNE
}

__device__ __forceinline__ float bf2f(unsigned short b) {
  union { unsigned int u; float f; } v; v.u = ((unsigned int)b) << 16;
  return v.f;
}

__device__ __forceinline__ void gload16(const void* g, void* l) {
  __builtin_amdgcn_global_load_lds(
      (const __attribute__((address_space(1))) void*)g,
      (__attribute__((address_space(3))) void*)l, 16, 0, 0);
}

// ---------------- gating: logits, top-2, softmax + x->bf16 + LDS histogram ----------------
__global__ __launch_bounds__(256) void gating_kernel(
    const float* __restrict__ x, const float* __restrict__ Wg,
    unsigned short* __restrict__ XB,
    int* __restrict__ top_e, float* __restrict__ top_p,
    int* __restrict__ hist, float* __restrict__ impp)
{
  __shared__ float wgs[NE][D_DIM];
  __shared__ int   h[NE];
  __shared__ float im[NE];
  const int tid = threadIdx.x;
  for (int i = tid; i < D_DIM * NE; i += 256)
    wgs[i & 7][i >> 3] = Wg[i];
  if (tid < NE) { h[tid] = 0; im[tid] = 0.f; }
  __syncthreads();

  const int lane = tid & 63;
  const int wave = tid >> 6;
  const int t = blockIdx.x * 4 + wave;

  float acc[NE];
#pragma unroll
  for (int e = 0; e < NE; e++) acc[e] = 0.f;
#pragma unroll
  for (int j = 0; j < 8; j++) {
    const int d = lane + j * 64;
    const float xv = x[(size_t)t * D_DIM + d];
    XB[(size_t)t * D_DIM + d] = f2bf(xv);       // fused x->bf16 (coalesced 2B/lane)
#pragma unroll
    for (int e = 0; e < NE; e++) acc[e] += xv * wgs[e][d];
  }
#pragma unroll
  for (int e = 0; e < NE; e++) {
#pragma unroll
    for (int m = 32; m > 0; m >>= 1) acc[e] += __shfl_xor(acc[e], m);
  }

  if (lane == 0) {
    int i0 = 0; float v0 = acc[0];
#pragma unroll
    for (int e = 1; e < NE; e++) if (acc[e] > v0) { v0 = acc[e]; i0 = e; }
    int i1 = -1; float v1 = -3.4e38f;
#pragma unroll
    for (int e = 0; e < NE; e++) if (e != i0 && acc[e] > v1) { v1 = acc[e]; i1 = e; }

    const float ex = __expf(v1 - v0);
    const float inv = 1.f / (1.f + ex);
    const float p0 = inv, p1 = ex * inv;
    top_e[t * 2 + 0] = i0; top_e[t * 2 + 1] = i1;
    top_p[t * 2 + 0] = p0; top_p[t * 2 + 1] = p1;
    atomicAdd(&h[i0], 1);  atomicAdd(&h[i1], 1);     // LDS atomics only
    atomicAdd(&im[i0], p0); atomicAdd(&im[i1], p1);
  }
  __syncthreads();
  if (tid < NE) {
    hist[blockIdx.x * NE + tid] = h[tid];
    impp[blockIdx.x * NE + tid] = im[tid];
  }
}

// ---------------- W1/W2 -> bf16, transposed per expert (64x64 tiles) ----------------
__global__ __launch_bounds__(256) void wtrans_kernel(
    const float* __restrict__ W1, const float* __restrict__ W2,
    unsigned short* __restrict__ W1T, unsigned short* __restrict__ W2T) {
  __shared__ unsigned short lds[64][76];   // stride 152B: 8B-aligned, banks staggered
  int bid = blockIdx.x;
  const float* src; unsigned short* dst; int R, C, lc;
  if (bid < 1024) { src = W1; dst = W1T; R = D_DIM; C = H_DIM; lc = 4; }
  else { bid -= 1024; src = W2; dst = W2T; R = H_DIM; C = D_DIM; lc = 3; }
  const int e = bid >> 7;                 // 128 tiles per expert
  const int rem = bid & 127;
  const int rt = rem >> lc;
  const int ct = rem & ((C >> 6) - 1);
  const size_t ebase = (size_t)e * R * C;
  const int tid = threadIdx.x;
#pragma unroll
  for (int it = 0; it < 4; it++) {        // read 64x64 f32, cvt to bf16 in LDS
    const int idx = it * 256 + tid;
    const int r = idx >> 4, c0 = (idx & 15) * 4;
    const float4 v = *reinterpret_cast<const float4*>(
        &src[ebase + (size_t)(rt * 64 + r) * C + ct * 64 + c0]);
    us4 o; o[0] = f2bf(v.x); o[1] = f2bf(v.y); o[2] = f2bf(v.z); o[3] = f2bf(v.w);
    *reinterpret_cast<us4*>(&lds[r][c0]) = o;
  }
  __syncthreads();
#pragma unroll
  for (int it = 0; it < 2; it++) {        // write transposed, 16B/lane full lines
    const int idx = it * 256 + tid;
    const int dc = idx >> 3;              // dst row (source col), 0..63
    const int c8 = idx & 7;               // 8 us8 chunks per dst row
    us8 o;
#pragma unroll
    for (int m = 0; m < 8; m++) o[m] = lds[c8 * 8 + m][dc];
    *reinterpret_cast<us8*>(&dst[ebase + (size_t)(ct * 64 + dc) * R + rt * 64 + c8 * 8]) = o;
  }
}

// ---------------- finalize: parallel reduce + offsets + losses + scatter bases ----------------
__global__ __launch_bounds__(512) void finalize_kernel(
    const int* __restrict__ hist, const float* __restrict__ impp,
    int* __restrict__ counts, float* __restrict__ importance,
    int* __restrict__ offsets, int* __restrict__ bb,
    float* __restrict__ out_tail)
{
  __shared__ int   ccnt[NSB][NE];   // per-scatter-block chunk sums
  __shared__ float cimp[NSB][NE];
  __shared__ int   cnt_s[NE];
  __shared__ float imp_s[NE];
  __shared__ int   off_s[NE];
  const int tid = threadIdx.x;
  // phase A: 512 threads, each sums 32 gating blocks for one (scatter-blk, expert)
  {
    const int s = tid >> 3, e = tid & 7;
    int c = 0; float im = 0.f;
#pragma unroll 8
    for (int j = 0; j < 32; j++) {
      c  += hist[(s * 32 + j) * NE + e];
      im += impp[(s * 32 + j) * NE + e];
    }
    ccnt[s][e] = c; cimp[s][e] = im;
  }
  __syncthreads();
  // phase B: per-expert totals
  if (tid < NE) {
    int cc = 0; float ss = 0.f;
#pragma unroll 8
    for (int q = 0; q < NSB; q++) { cc += ccnt[q][tid]; ss += cimp[q][tid]; }
    cnt_s[tid] = cc; imp_s[tid] = ss;
    counts[tid] = cc; importance[tid] = ss;
  }
  __syncthreads();
  // phase C: offsets + losses (scalar, trivial)
  if (tid == 0) {
    int off = 0;
    for (int e = 0; e < NE; e++) { off_s[e] = off; offsets[e] = off; off += cnt_s[e]; }
    float mi = 0.f, ml = 0.f;
    for (int e = 0; e < NE; e++) { mi += imp_s[e]; ml += (float)cnt_s[e]; }
    mi *= (1.f / NE); ml *= (1.f / NE);
    float vi = 0.f, vl = 0.f;
    for (int e = 0; e < NE; e++) {
      const float di = imp_s[e] - mi; vi += di * di;
      const float dl = (float)cnt_s[e] - ml; vl += dl * dl;
    }
    vi *= (1.f / (NE - 1)); vl *= (1.f / (NE - 1));   // ddof=1
    out_tail[0] = vi / (mi * mi + 1e-10f);
    out_tail[1] = vl / (ml * ml + 1e-10f);
  }
  __syncthreads();
  // phase D: scatter-block bases (64-step LDS walk per expert)
  if (tid < NE) {
    int run = off_s[tid];
    for (int q = 0; q < NSB; q++) { bb[q * NE + tid] = run; run += ccnt[q][tid]; }
  }
}

// ---------------- scatter: slot assignment via LDS cursors + inverse map ----------------
__global__ __launch_bounds__(256) void scatter_kernel(
    const int* __restrict__ top_e, const int* __restrict__ bb,
    int* __restrict__ tok_list, int* __restrict__ inv_slot)
{
  __shared__ int cur[NE];
  const int tid = threadIdx.x;
  if (tid < NE) cur[tid] = bb[blockIdx.x * NE + tid];
  __syncthreads();
  const int i = blockIdx.x * 256 + tid;
  const int e = top_e[i];
  const int pos = atomicAdd(&cur[e], 1);   // LDS atomic: intra-block only
  tok_list[pos] = i >> 1;
  inv_slot[i] = pos;
}

// ---------------- MFMA expert GEMM: 128x128 tile, 4 waves, 64x64/wave,
//   dbuf LDS + raw-barrier counted-vmcnt schedule (no vmcnt(0) drain in loop;
//   2-tile lookahead; residual stalls covered by the 2nd resident block/CU)
// STAGE2=false: Hout[slot][h] = relu(C + b1)  (OD=H_DIM)
// STAGE2=true : Hout[slot][d] =      C + b2   (OD=D_DIM, un-gated expert output)
template<int KD, int MTILES, bool STAGE2>
__global__ __launch_bounds__(256) void expert_gemm_kernel(
    const unsigned short* __restrict__ Wt,
    const unsigned short* __restrict__ Bsrc,
    const float* __restrict__ bias,
    const int* __restrict__ counts, const int* __restrict__ offsets,
    const int* __restrict__ tok_list,
    unsigned short* __restrict__ Hout)
{
  constexpr int M = MTILES * 128;
  constexpr int LMT = (MTILES == 8) ? 3 : 2;
  constexpr int OD = STAGE2 ? D_DIM : H_DIM;
  constexpr int NK = KD / 64;
  const int e = blockIdx.x & 7;          // expert -> fixed XCD for weight L2 residency
  const int tmp = blockIdx.x >> 3;
  const int mtile = tmp & (MTILES - 1);
  const int ttile = tmp >> LMT;          // 0..127: covers any routing imbalance
  const int cnt = counts[e];
  if (ttile * 128 >= cnt) return;
  const int base = offsets[e] + ttile * 128;
  const int rem = cnt - ttile * 128;
  const int nvalid = rem < 128 ? rem : 128;

  __shared__ unsigned short Ws[2][128][64];   // 32 KB (double-buffered)
  __shared__ unsigned short Xs[2][128][64];   // 32 KB

  const int tid = threadIdx.x;
  const int lane = tid & 63;
  const int wave = tid >> 6;
  const int wm = wave & 1, wn = wave >> 1;

  // staging sources: 4 x 16B segs per thread per matrix per K-tile; LDS dest linear,
  // swizzle applied on the GLOBAL column (both-sides involution)
  const unsigned short* wsrc[4];
  const unsigned short* bsrc[4];
#pragma unroll
  for (int i = 0; i < 4; i++) {
    const int seg = tid + i * 256;
    const int row = seg >> 3;
    const int s = seg & 7;
    const int scol = ((s ^ (row & 7)) << 3);
    wsrc[i] = Wt + ((size_t)e * M + (size_t)(mtile * 128 + row)) * KD + scol;
    const int cr = (row < nvalid) ? row : (nvalid - 1);
    const int brow = STAGE2 ? (base + cr) : tok_list[base + cr];
    bsrc[i] = Bsrc + (size_t)brow * KD + scol;
  }
  const int ldso = wave * 512;   // ushort elems; HW adds lane*16B

  f32x4 acc[4][4];
#pragma unroll
  for (int mi = 0; mi < 4; mi++)
#pragma unroll
    for (int nj = 0; nj < 4; nj++)
#pragma unroll
      for (int q = 0; q < 4; q++) acc[mi][nj][q] = 0.f;

#define STAGE_TILE(t_)                                                        \
  {                                                                           \
    const int buf_ = (t_) & 1;                                                \
    const int k0_ = (t_) * 64;                                                \
    _Pragma("unroll")                                                         \
    for (int i = 0; i < 4; i++) {                                             \
      gload16(wsrc[i] + k0_, &Ws[buf_][0][0] + ldso + i * 2048);              \
      gload16(bsrc[i] + k0_, &Xs[buf_][0][0] + ldso + i * 2048);              \
    }                                                                         \
  }

  // prologue: stage K-tiles 0 and 1 (8 loads each); wait tile-0 only
  STAGE_TILE(0)
  STAGE_TILE(1)
  asm volatile("s_waitcnt vmcnt(8)" ::: "memory");
  __builtin_amdgcn_s_barrier();

  for (int t = 0; t < NK; ++t) {
    const int buf = t & 1;
    bf16x8 a[4][2], b[4][2];
    // ds_read all fragments of this wave from buf (tile t is resident)
#pragma unroll
    for (int mi = 0; mi < 4; mi++) {
      const int m = wm * 64 + mi * 16 + (lane & 15);
#pragma unroll
      for (int ks = 0; ks < 2; ks++) {
        const int sl = ((ks * 4 + (lane >> 4)) ^ (m & 7)) << 3;
        a[mi][ks] = *reinterpret_cast<const bf16x8*>(&Ws[buf][m][sl]);
      }
    }
#pragma unroll
    for (int nj = 0; nj < 4; nj++) {
      const int r = wn * 64 + nj * 16 + (lane & 15);
#pragma unroll
      for (int ks = 0; ks < 2; ks++) {
        const int sl = ((ks * 4 + (lane >> 4)) ^ (r & 7)) << 3;
        b[nj][ks] = *reinterpret_cast<const bf16x8*>(&Xs[buf][r][sl]);
      }
    }
    asm volatile("s_waitcnt lgkmcnt(0)" ::: "memory");   // frags in regs
    __builtin_amdgcn_sched_barrier(0);                   // rule 18: pin MFMA below
    __builtin_amdgcn_s_barrier();                        // all waves done reading buf
    if (t + 2 < NK) {
      STAGE_TILE(t + 2)                                  // overwrite buf (now free)
      asm volatile("s_waitcnt vmcnt(8)" ::: "memory");   // tile t+1 landed; t+2 in flight
    } else {
      asm volatile("s_waitcnt vmcnt(0)" ::: "memory");   // tail drain
    }
    __builtin_amdgcn_s_barrier();                        // tile t+1 visible to all waves
    __builtin_amdgcn_s_setprio(1);
#pragma unroll
    for (int ks = 0; ks < 2; ks++)
#pragma unroll
      for (int mi = 0; mi < 4; mi++)
#pragma unroll
        for (int nj = 0; nj < 4; nj++)
          acc[mi][nj] = __builtin_amdgcn_mfma_f32_16x16x32_bf16(a[mi][ks], b[nj][ks], acc[mi][nj], 0, 0, 0);
    __builtin_amdgcn_s_setprio(0);
  }
#undef STAGE_TILE

  // epilogue: m_loc = wm*64+mi*16+(lane>>4)*4+j (weight dim), n_loc = wn*64+nj*16+(lane&15) (slot)
#pragma unroll
  for (int mi = 0; mi < 4; mi++) {
    const int mb = mtile * 128 + wm * 64 + mi * 16 + ((lane >> 4) << 2);
    float bv[4];
#pragma unroll
    for (int j = 0; j < 4; j++) bv[j] = bias[e * M + mb + j];
#pragma unroll
    for (int nj = 0; nj < 4; nj++) {
      const int r = wn * 64 + nj * 16 + (lane & 15);
      if (r < nvalid) {
        us4 o;
#pragma unroll
        for (int j = 0; j < 4; j++) {
          const float v = acc[mi][nj][j] + bv[j];
          o[j] = f2bf(STAGE2 ? v : fmaxf(v, 0.f));
        }
        *reinterpret_cast<us4*>(&Hout[(size_t)(base + r) * OD + mb]) = o;
      }
    }
  }
}

// ---------------- combine: out[t] = p0*EO[s0] + p1*EO[s1] ----------------
__global__ __launch_bounds__(256) void combine_kernel(
    const unsigned short* __restrict__ EO,
    const int* __restrict__ inv_slot, const float* __restrict__ top_p,
    float* __restrict__ out)
{
  const int idx = blockIdx.x * 256 + threadIdx.x;
  const int t  = idx >> 6;            // 64 threads per token (512/8)
  const int d0 = (idx & 63) * 8;
  const int s0 = inv_slot[t * 2 + 0];
  const int s1 = inv_slot[t * 2 + 1];
  const float p0 = top_p[t * 2 + 0];
  const float p1 = top_p[t * 2 + 1];
  const us8 a = *reinterpret_cast<const us8*>(&EO[(size_t)s0 * D_DIM + d0]);
  const us8 b = *reinterpret_cast<const us8*>(&EO[(size_t)s1 * D_DIM + d0]);
  float4 o0, o1;
  o0.x = p0 * bf2f(a[0]) + p1 * bf2f(b[0]);
  o0.y = p0 * bf2f(a[1]) + p1 * bf2f(b[1]);
  o0.z = p0 * bf2f(a[2]) + p1 * bf2f(b[2]);
  o0.w = p0 * bf2f(a[3]) + p1 * bf2f(b[3]);
  o1.x = p0 * bf2f(a[4]) + p1 * bf2f(b[4]);
  o1.y = p0 * bf2f(a[5]) + p1 * bf2f(b[5]);
  o1.z = p0 * bf2f(a[6]) + p1 * bf2f(b[6]);
  o1.w = p0 * bf2f(a[7]) + p1 * bf2f(b[7]);
  float* op = &out[(size_t)t * D_DIM + d0];
  *reinterpret_cast<float4*>(op)     = o0;
  *reinterpret_cast<float4*>(op + 4) = o1;
}

// ---------------- launcher ----------------
extern "C" void kernel_launch(void* const* d_in, const int* in_sizes, int n_in,
                              void* d_out, int out_size, void* d_ws, size_t ws_size,
                              hipStream_t stream)
{
  const float* x  = (const float*)d_in[0];
  const float* Wg = (const float*)d_in[1];
  const float* W1 = (const float*)d_in[2];
  const float* b1 = (const float*)d_in[3];
  const float* W2 = (const float*)d_in[4];
  const float* b2 = (const float*)d_in[5];
  float* out = (float*)d_out;

  char* ws = (char*)d_ws;
  int*   counts     = (int*)(ws + 0);
  float* importance = (float*)(ws + 32);
  int*   offsets    = (int*)(ws + 64);
  int*   top_e      = (int*)(ws + 128);
  float* top_p      = (float*)(ws + 128 + 65536);
  int*   tok_list   = (int*)(ws + 128 + 131072);
  int*   hist       = (int*)(ws + 262400);
  float* impp       = (float*)(ws + 328064);
  int*   bb         = (int*)(ws + 393728);
  int*   inv_slot   = (int*)(ws + 395776);
  unsigned short* XB   = (unsigned short*)(ws + (1ull << 20));
  unsigned short* W1T  = (unsigned short*)(ws + (9ull << 20));
  unsigned short* W2T  = (unsigned short*)(ws + (17ull << 20));
  unsigned short* HBUF = (unsigned short*)(ws + (25ull << 20));
  unsigned short* EO   = (unsigned short*)(ws + (1ull << 20));  // aliases XB+W1T (dead after stage1)

  gating_kernel<<<NGB, 256, 0, stream>>>(x, Wg, XB, top_e, top_p, hist, impp);
  wtrans_kernel<<<2048, 256, 0, stream>>>(W1, W2, W1T, W2T);
  finalize_kernel<<<1, 512, 0, stream>>>(hist, impp, counts, importance, offsets, bb,
                                         out + (size_t)T_TOK * D_DIM);
  scatter_kernel<<<NSB, 256, 0, stream>>>(top_e, bb, tok_list, inv_slot);
  // stage 1: HBUF = relu(x @ W1 + b1)   (M=1024 -> 8 mtiles, K=512)
  expert_gemm_kernel<512, 8, false><<<8 * 8 * 128, 256, 0, stream>>>(
      W1T, XB, b1, counts, offsets, tok_list, HBUF);
  // stage 2: EO = HBUF @ W2 + b2        (M=512 -> 4 mtiles, K=1024)
  expert_gemm_kernel<1024, 4, true><<<8 * 4 * 128, 256, 0, stream>>>(
      W2T, HBUF, b2, counts, offsets, tok_list, EO);
  // combine: out[t] = p0*EO[s0] + p1*EO[s1]
  combine_kernel<<<T_TOK * D_DIM / (256 * 8), 256, 0, stream>>>(EO, inv_slot, top_p, out);
}